// Round 1
// baseline (268.388 us; speedup 1.0000x reference)
//
#include <hip/hip_runtime.h>
#include <hip/hip_bf16.h>

#define F 256
#define V 512
#define NB 8   // texture batch
#define NC 8   // n_code
#define NH 4
#define DQ 64
#define EPS 1e-6f

typedef __hip_bfloat16 bf16;
typedef __attribute__((ext_vector_type(8))) short short8;   // 8 bf16 MFMA operand
typedef __attribute__((ext_vector_type(4))) float f32x4;    // MFMA accumulator
typedef __attribute__((ext_vector_type(4))) unsigned uint4v;

__device__ __forceinline__ float b2f(bf16 x){ return __bfloat162float(x); }
__device__ __forceinline__ float shf(short s){
    return __bfloat162float(__builtin_bit_cast(bf16, (unsigned short)s));
}

#define MFMA(a,b,c) __builtin_amdgcn_mfma_f32_16x16x32_bf16((a),(b),(c),0,0,0)

__device__ __forceinline__ unsigned pack2bf(float a, float b){
    unsigned short ua = __builtin_bit_cast(unsigned short, __float2bfloat16(a));
    unsigned short ub = __builtin_bit_cast(unsigned short, __float2bfloat16(b));
    return (unsigned)ua | ((unsigned)ub << 16);
}

// ---- K0: cast the six 256x256 fp32 weights -> bf16 ws. order Wq,Wk,Wv,Wo,W1,W2.
// vectorized x4: grid 6*64 blocks of 256 threads.
__global__ void castw_kernel(const float* __restrict__ w0, const float* __restrict__ w1,
                             const float* __restrict__ w2, const float* __restrict__ w3,
                             const float* __restrict__ w4, const float* __restrict__ w5,
                             bf16* __restrict__ dst){
    int which = blockIdx.x >> 6;
    int idx = (((blockIdx.x & 63) << 8) | threadIdx.x) << 2;
    const float* s = which==0?w0: which==1?w1: which==2?w2: which==3?w3: which==4?w4: w5;
    float4 v = *(const float4*)(s + idx);
    uint2 p; p.x = pack2bf(v.x, v.y); p.y = pack2bf(v.z, v.w);
    *(uint2*)(dst + which * (F*F) + idx) = p;
}

// ---- K1: LayerNorm -> bf16 normalized rows; also emits bf16 copy of texture_map (tb)
// wave-per-row, shuffle reduce, no barriers. grid 2048 x 256 thr (4 rows/block).
__global__ __launch_bounds__(256) void ln_kernel(const float* __restrict__ code,
                          const float* __restrict__ tex,
                          const float* __restrict__ ln1_g, const float* __restrict__ ln1_b,
                          const float* __restrict__ ln2_g, const float* __restrict__ ln2_b,
                          bf16* __restrict__ cn, bf16* __restrict__ tn, bf16* __restrict__ tb){
    int w = threadIdx.x >> 6, lane = threadIdx.x & 63;
    int r = blockIdx.x * 4 + w;
    int is_tex = r >> 12;
    int row = r & 4095;
    const float* src = is_tex ? tex : code;
    const float* g   = is_tex ? ln2_g : ln1_g;
    const float* be  = is_tex ? ln2_b : ln1_b;
    bf16* dst        = is_tex ? tn : cn;

    float4 x = *(const float4*)(src + row * F + lane * 4);
    if (is_tex){
        uint2 p; p.x = pack2bf(x.x, x.y); p.y = pack2bf(x.z, x.w);
        *(uint2*)(tb + row * F + lane * 4) = p;
    }
    float s = x.x + x.y + x.z + x.w;
    #pragma unroll
    for(int m = 1; m < 64; m <<= 1) s += __shfl_xor(s, m);
    float mu = s * (1.0f / F);
    float d0 = x.x - mu, d1 = x.y - mu, d2 = x.z - mu, d3 = x.w - mu;
    float q = d0*d0 + d1*d1 + d2*d2 + d3*d3;
    #pragma unroll
    for(int m = 1; m < 64; m <<= 1) q += __shfl_xor(q, m);
    float rs = rsqrtf(q * (1.0f / F) + EPS);
    float4 gg = *(const float4*)(g + lane * 4);
    float4 bb = *(const float4*)(be + lane * 4);
    uint2 p;
    p.x = pack2bf(d0 * rs * gg.x + bb.x, d1 * rs * gg.y + bb.y);
    p.y = pack2bf(d2 * rs * gg.z + bb.z, d3 * rs * gg.w + bb.w);
    *(uint2*)(dst + row * F + lane * 4) = p;
}

// ---- K2: QKV MFMA GEMM, M=4096 N=256 K=256. grid (64, 4, 3), 4 waves of 16x64.
// z=0: Q -> qn row-major; z=1: K -> kn row-major; z=2: V -> v4 chunk-tiled.
// All stores staged through LDS and written as coalesced 16B stores.
__global__ __launch_bounds__(256) __attribute__((amdgpu_waves_per_eu(2,3)))
void qkv_kernel(const bf16* __restrict__ cn,
                const bf16* __restrict__ tn,
                const bf16* __restrict__ wbf,
                const float* __restrict__ bq,
                const float* __restrict__ bk,
                const float* __restrict__ bv,
                bf16* __restrict__ qn,
                bf16* __restrict__ kn,
                bf16* __restrict__ v4){
    __shared__ bf16 ts[64][72];
    int which = blockIdx.z;
    const bf16* in   = (which == 0) ? tn : cn;
    const bf16* wb   = wbf + which * (F * F);
    const float* bias = (which == 0) ? bq : (which == 1) ? bk : bv;

    int tid = threadIdx.x;
    int w = tid >> 6, lane = tid & 63;
    int lg = lane >> 4, li = lane & 15;
    int rowbase = blockIdx.x * 64 + w * 16;
    int colbase = blockIdx.y * 64;

    f32x4 acc[4];
    #pragma unroll
    for(int ni = 0; ni < 4; ni++) acc[ni] = (f32x4){0.f,0.f,0.f,0.f};

    const bf16* arow = in + (rowbase + li) * F + lg * 8;
    const bf16* brow = wb + (colbase + li) * F + lg * 8;

    #pragma unroll
    for(int kc = 0; kc < 8; kc++){
        short8 a = *(const short8*)(arow + kc * 32);
        #pragma unroll
        for(int ni = 0; ni < 4; ni++){
            short8 bbf = *(const short8*)(brow + ni * 16 * F + kc * 32);
            acc[ni] = MFMA(a, bbf, acc[ni]);
        }
    }

    // stage (acc + bias) to LDS; V goes in transposed [col][row]
    if (which < 2){
        #pragma unroll
        for(int ni = 0; ni < 4; ni++)
            #pragma unroll
            for(int r = 0; r < 4; r++)
                ts[w * 16 + lg * 4 + r][ni * 16 + li] =
                    __float2bfloat16(acc[ni][r] + bias[colbase + ni * 16 + li]);
    } else {
        #pragma unroll
        for(int ni = 0; ni < 4; ni++)
            #pragma unroll
            for(int r = 0; r < 4; r++)
                ts[ni * 16 + li][w * 16 + lg * 4 + r] =
                    __float2bfloat16(acc[ni][r] + bias[colbase + ni * 16 + li]);
    }
    __syncthreads();

    if (which < 2){
        bf16* outp = which ? kn : qn;
        int rr = tid >> 2, gg2 = tid & 3;
        *(short8*)(outp + (blockIdx.x * 64 + rr) * F + colbase + gg2 * 16)
            = *(const short8*)&ts[rr][gg2 * 16];
    } else {
        int col = tid & 63, half = tid >> 6;
        int keybase = blockIdx.x * 64;
        int n = keybase >> 9;
        int keyl = (keybase & (V - 1)) + half * 16;
        int chunk = keyl >> 5, off = keyl & 31;
        *(short8*)(v4 + ((n * 16 + chunk) * F + colbase + col) * 32 + off)
            = *(const short8*)&ts[col][half * 16];
    }
}

// ---- K3 MEGA: flash attention + Wo + tex residual + ffln LN + W1/ReLU + W2 + residual -> out.
// grid (64, 16): x encodes (n = x&7 -> XCD swizzle, b = x>>3), y = qtile. 512 thr = 8 waves.
// 2-deep rotating K/V prefetch, waves_per_eu(4,4) so the compiler keeps the pipeline live.
#define BLOAD(Wp, kcc, nii) (*(const short8*)((Wp) + (colbase + (nii)*16 + li) * F + (kcc) * 32 + lg * 8))

__global__ __launch_bounds__(512, 4) __attribute__((amdgpu_waves_per_eu(4,4)))
void attn_mlp_kernel(const bf16* __restrict__ qn,
                     const bf16* __restrict__ kn,
                     const bf16* __restrict__ v4,
                     const bf16* __restrict__ wbf,
                     const float* __restrict__ bo,
                     const bf16* __restrict__ tb,
                     const float* __restrict__ ffg,
                     const float* __restrict__ ffb,
                     const float* __restrict__ b1,
                     const float* __restrict__ b2,
                     float* __restrict__ out){
    __shared__ bf16 xs[32][264];        // ctx -> x -> xhat -> h1 (reused)
    __shared__ float red[512], red2[512];
    __shared__ float stat[32][2];
    int n = blockIdx.x & 7, b = blockIdx.x >> 3, qt = blockIdx.y;
    int tid = threadIdx.x;
    int w = tid >> 6, lane = tid & 63;
    int h = w & 3, qh = w >> 2;
    int lg = lane >> 4, li = lane & 15;

    // Q B-frag resident
    short8 qB[2];
    #pragma unroll
    for(int ks = 0; ks < 2; ks++)
        qB[ks] = *(const short8*)(qn + (b * V + qt * 32 + qh * 16 + li) * F
                                     + h * DQ + ks * 32 + lg * 8);

    f32x4 o[4];
    #pragma unroll
    for(int dt = 0; dt < 4; dt++) o[dt] = (f32x4){0.f,0.f,0.f,0.f};
    float l_acc = 0.f;

    const float scale = 0.125f;
    int g1 = lg & 1;
    int lhA = li | ((2 * g1) << 4);
    int lhB = lhA | 16;
    bool hi = lane >= 32;

    // per-lane bases: K row-major, V chunk-tiled
    const bf16* kb_ = kn + (n * V + li) * F + h * DQ + lg * 8;
    const bf16* vb_ = v4 + (n * 16 * F + h * DQ) * 32 + li * 32 + lg * 8;

    // 2-deep rotating prefetch buffers
    short8 kbuf[2][4], vbuf[2][4];
    #pragma unroll
    for(int c = 0; c < 2; c++){
        kbuf[c][0] = *(const short8*)(kb_ + (c * 32 +  0) * F);
        kbuf[c][1] = *(const short8*)(kb_ + (c * 32 +  0) * F + 32);
        kbuf[c][2] = *(const short8*)(kb_ + (c * 32 + 16) * F);
        kbuf[c][3] = *(const short8*)(kb_ + (c * 32 + 16) * F + 32);
        vbuf[c][0] = *(const short8*)(vb_ + (c * F +  0) * 32);
        vbuf[c][1] = *(const short8*)(vb_ + (c * F + 16) * 32);
        vbuf[c][2] = *(const short8*)(vb_ + (c * F + 32) * 32);
        vbuf[c][3] = *(const short8*)(vb_ + (c * F + 48) * 32);
    }

    #pragma unroll
    for(int kc = 0; kc < 16; kc++){
        const int cur = kc & 1;
        // S^T = K·Q^T
        f32x4 st0 = (f32x4){0.f,0.f,0.f,0.f};
        f32x4 st1 = (f32x4){0.f,0.f,0.f,0.f};
        __builtin_amdgcn_s_setprio(1);
        st0 = MFMA(kbuf[cur][0], qB[0], st0);
        st1 = MFMA(kbuf[cur][2], qB[0], st1);
        st0 = MFMA(kbuf[cur][1], qB[1], st0);
        st1 = MFMA(kbuf[cur][3], qB[1], st1);
        __builtin_amdgcn_s_setprio(0);
        // K buffers for this slot are free now: prefetch chunk kc+2
        if (kc < 14){
            kbuf[cur][0] = *(const short8*)(kb_ + ((kc + 2) * 32 +  0) * F);
            kbuf[cur][1] = *(const short8*)(kb_ + ((kc + 2) * 32 +  0) * F + 32);
            kbuf[cur][2] = *(const short8*)(kb_ + ((kc + 2) * 32 + 16) * F);
            kbuf[cur][3] = *(const short8*)(kb_ + ((kc + 2) * 32 + 16) * F + 32);
        }

        // exp (no max: bounded scores, ratio-invariant)
        float p[2][4], rsum = 0.f;
        #pragma unroll
        for(int r = 0; r < 4; r++){
            p[0][r] = __expf(st0[r] * scale);
            p[1][r] = __expf(st1[r] * scale);
            rsum += p[0][r] + p[1][r];
        }
        l_acc += rsum;

        unsigned pk00 = pack2bf(p[0][0], p[0][1]);
        unsigned pk01 = pack2bf(p[0][2], p[0][3]);
        unsigned pk10 = pack2bf(p[1][0], p[1][1]);
        unsigned pk11 = pack2bf(p[1][2], p[1][3]);

        unsigned d0a = __shfl((int)pk00, lhA, 64);
        unsigned d0b = __shfl((int)pk10, lhA, 64);
        unsigned d1a = __shfl((int)pk01, lhA, 64);
        unsigned d1b = __shfl((int)pk11, lhA, 64);
        unsigned d2a = __shfl((int)pk00, lhB, 64);
        unsigned d2b = __shfl((int)pk10, lhB, 64);
        unsigned d3a = __shfl((int)pk01, lhB, 64);
        unsigned d3b = __shfl((int)pk11, lhB, 64);
        uint4v uv;
        uv.x = hi ? d0b : d0a;
        uv.y = hi ? d1b : d1a;
        uv.z = hi ? d2b : d2a;
        uv.w = hi ? d3b : d3a;
        short8 pfrag = __builtin_bit_cast(short8, uv);

        __builtin_amdgcn_s_setprio(1);
        o[0] = MFMA(vbuf[cur][0], pfrag, o[0]);
        o[1] = MFMA(vbuf[cur][1], pfrag, o[1]);
        o[2] = MFMA(vbuf[cur][2], pfrag, o[2]);
        o[3] = MFMA(vbuf[cur][3], pfrag, o[3]);
        __builtin_amdgcn_s_setprio(0);
        // V buffers for this slot are free now: prefetch chunk kc+2
        if (kc < 14){
            vbuf[cur][0] = *(const short8*)(vb_ + ((kc + 2) * F +  0) * 32);
            vbuf[cur][1] = *(const short8*)(vb_ + ((kc + 2) * F + 16) * 32);
            vbuf[cur][2] = *(const short8*)(vb_ + ((kc + 2) * F + 32) * 32);
            vbuf[cur][3] = *(const short8*)(vb_ + ((kc + 2) * F + 48) * 32);
        }
    }

    l_acc += __shfl_xor(l_acc, 16);
    l_acc += __shfl_xor(l_acc, 32);
    float inv = 1.0f / l_acc;

    // stage normalized O to LDS as ctx[qrel][col]
    #pragma unroll
    for(int dt = 0; dt < 4; dt++){
        uint2 pkd;
        pkd.x = pack2bf(o[dt][0] * inv, o[dt][1] * inv);
        pkd.y = pack2bf(o[dt][2] * inv, o[dt][3] * inv);
        *(uint2*)&xs[qh * 16 + li][h * DQ + dt * 16 + lg * 4] = pkd;
    }

    // hoist tex-residual loads: independent of xs, overlap the barrier + Wo GEMM
    int colbase = w * 32;
    float tres[2][2][4];
    #pragma unroll
    for(int mi = 0; mi < 2; mi++)
        #pragma unroll
        for(int r = 0; r < 4; r++){
            int qrel = mi * 16 + lg * 4 + r;
            #pragma unroll
            for(int ni = 0; ni < 2; ni++)
                tres[mi][ni][r] = b2f(tb[(b * V + qt * 32 + qrel) * F + colbase + ni * 16 + li]);
        }
    __syncthreads();

    // ---- Wo GEMM + bo + tex residual -> xres (registers, fp32), B-loads pipelined 2 deep
    const bf16* Wo = wbf + 3 * (F * F);
    f32x4 xac[2][2];
    #pragma unroll
    for(int mi = 0; mi < 2; mi++)
        #pragma unroll
        for(int ni = 0; ni < 2; ni++) xac[mi][ni] = (f32x4){0.f,0.f,0.f,0.f};
    {
        short8 bw[2][2];
        bw[0][0] = BLOAD(Wo, 0, 0); bw[0][1] = BLOAD(Wo, 0, 1);
        bw[1][0] = BLOAD(Wo, 1, 0); bw[1][1] = BLOAD(Wo, 1, 1);
        #pragma unroll
        for(int kc = 0; kc < 8; kc++){
            short8 a0 = *(const short8*)&xs[li][kc * 32 + lg * 8];
            short8 a1 = *(const short8*)&xs[16 + li][kc * 32 + lg * 8];
            xac[0][0] = MFMA(a0, bw[kc & 1][0], xac[0][0]);
            xac[1][0] = MFMA(a1, bw[kc & 1][0], xac[1][0]);
            xac[0][1] = MFMA(a0, bw[kc & 1][1], xac[0][1]);
            xac[1][1] = MFMA(a1, bw[kc & 1][1], xac[1][1]);
            if (kc < 6){
                bw[kc & 1][0] = BLOAD(Wo, kc + 2, 0);
                bw[kc & 1][1] = BLOAD(Wo, kc + 2, 1);
            }
        }
    }
    float xres[2][2][4];
    #pragma unroll
    for(int mi = 0; mi < 2; mi++)
        #pragma unroll
        for(int r = 0; r < 4; r++){
            #pragma unroll
            for(int ni = 0; ni < 2; ni++){
                int col = colbase + ni * 16 + li;
                xres[mi][ni][r] = xac[mi][ni][r] + bo[col] + tres[mi][ni][r];
            }
        }
    __syncthreads();                  // all ctx reads done
    // write x (bf16) into xs
    #pragma unroll
    for(int mi = 0; mi < 2; mi++)
        #pragma unroll
        for(int r = 0; r < 4; r++){
            int qrel = mi * 16 + lg * 4 + r;
            #pragma unroll
            for(int ni = 0; ni < 2; ni++)
                xs[qrel][colbase + ni * 16 + li] = __float2bfloat16(xres[mi][ni][r]);
        }
    __syncthreads();

    // ---- ffln LN: 16 threads per row, one-pass (E[x^2]-mu^2)
    int row = tid >> 4, sub = tid & 15;
    short8 xa = *(const short8*)&xs[row][sub * 16];
    short8 xb2 = *(const short8*)&xs[row][sub * 16 + 8];
    float sum = 0.f, sq = 0.f;
    #pragma unroll
    for(int j = 0; j < 8; j++){
        float v0 = shf(xa[j]), v1 = shf(xb2[j]);
        sum += v0 + v1; sq += v0 * v0 + v1 * v1;
    }
    red[tid] = sum; red2[tid] = sq;
    __syncthreads();
    if (tid < 32){
        float s = 0.f, q2 = 0.f;
        #pragma unroll
        for(int i = 0; i < 16; i++){ s += red[tid * 16 + i]; q2 += red2[tid * 16 + i]; }
        float mu = s * (1.0f / F);
        float var = q2 * (1.0f / F) - mu * mu;
        stat[tid][0] = mu;
        stat[tid][1] = rsqrtf(var + EPS);
    }
    __syncthreads();
    {
        float mu = stat[row][0], rsv = stat[row][1];
        float nv[16];
        #pragma unroll
        for(int j = 0; j < 8; j++){
            int c0 = sub * 16 + j, c1 = sub * 16 + 8 + j;
            nv[j]     = (shf(xa[j])  - mu) * rsv * ffg[c0] + ffb[c0];
            nv[8 + j] = (shf(xb2[j]) - mu) * rsv * ffg[c1] + ffb[c1];
        }
        uint4v pa, pb;
        pa.x = pack2bf(nv[0], nv[1]);  pa.y = pack2bf(nv[2], nv[3]);
        pa.z = pack2bf(nv[4], nv[5]);  pa.w = pack2bf(nv[6], nv[7]);
        pb.x = pack2bf(nv[8], nv[9]);  pb.y = pack2bf(nv[10], nv[11]);
        pb.z = pack2bf(nv[12], nv[13]); pb.w = pack2bf(nv[14], nv[15]);
        *(short8*)&xs[row][sub * 16]     = __builtin_bit_cast(short8, pa);
        *(short8*)&xs[row][sub * 16 + 8] = __builtin_bit_cast(short8, pb);
    }
    __syncthreads();

    // ---- GEMM1: h = relu(xhat @ W1^T + b1), wave cols w*32..+32, pipelined B
    const bf16* W1b = wbf + 4 * (F * F);
    f32x4 hac[2][2];
    #pragma unroll
    for(int mi = 0; mi < 2; mi++)
        #pragma unroll
        for(int ni = 0; ni < 2; ni++) hac[mi][ni] = (f32x4){0.f,0.f,0.f,0.f};
    {
        short8 bw[2][2];
        bw[0][0] = BLOAD(W1b, 0, 0); bw[0][1] = BLOAD(W1b, 0, 1);
        bw[1][0] = BLOAD(W1b, 1, 0); bw[1][1] = BLOAD(W1b, 1, 1);
        #pragma unroll
        for(int kc = 0; kc < 8; kc++){
            short8 a0 = *(const short8*)&xs[li][kc * 32 + lg * 8];
            short8 a1 = *(const short8*)&xs[16 + li][kc * 32 + lg * 8];
            hac[0][0] = MFMA(a0, bw[kc & 1][0], hac[0][0]);
            hac[1][0] = MFMA(a1, bw[kc & 1][0], hac[1][0]);
            hac[0][1] = MFMA(a0, bw[kc & 1][1], hac[0][1]);
            hac[1][1] = MFMA(a1, bw[kc & 1][1], hac[1][1]);
            if (kc < 6){
                bw[kc & 1][0] = BLOAD(W1b, kc + 2, 0);
                bw[kc & 1][1] = BLOAD(W1b, kc + 2, 1);
            }
        }
    }
    __syncthreads();                  // xhat reads done
    #pragma unroll
    for(int mi = 0; mi < 2; mi++)
        #pragma unroll
        for(int r = 0; r < 4; r++){
            int rr = mi * 16 + lg * 4 + r;
            #pragma unroll
            for(int ni = 0; ni < 2; ni++){
                int col = colbase + ni * 16 + li;
                xs[rr][col] = __float2bfloat16(fmaxf(hac[mi][ni][r] + b1[col], 0.f));
            }
        }
    __syncthreads();

    // ---- GEMM2: out = x + h @ W2^T + b2, pipelined B
    const bf16* W2b = wbf + 5 * (F * F);
    f32x4 oac[2][2];
    #pragma unroll
    for(int mi = 0; mi < 2; mi++)
        #pragma unroll
        for(int ni = 0; ni < 2; ni++) oac[mi][ni] = (f32x4){0.f,0.f,0.f,0.f};
    {
        short8 bw[2][2];
        bw[0][0] = BLOAD(W2b, 0, 0); bw[0][1] = BLOAD(W2b, 0, 1);
        bw[1][0] = BLOAD(W2b, 1, 0); bw[1][1] = BLOAD(W2b, 1, 1);
        #pragma unroll
        for(int kc = 0; kc < 8; kc++){
            short8 a0 = *(const short8*)&xs[li][kc * 32 + lg * 8];
            short8 a1 = *(const short8*)&xs[16 + li][kc * 32 + lg * 8];
            oac[0][0] = MFMA(a0, bw[kc & 1][0], oac[0][0]);
            oac[1][0] = MFMA(a1, bw[kc & 1][0], oac[1][0]);
            oac[0][1] = MFMA(a0, bw[kc & 1][1], oac[0][1]);
            oac[1][1] = MFMA(a1, bw[kc & 1][1], oac[1][1]);
            if (kc < 6){
                bw[kc & 1][0] = BLOAD(W2b, kc + 2, 0);
                bw[kc & 1][1] = BLOAD(W2b, kc + 2, 1);
            }
        }
    }
    #pragma unroll
    for(int mi = 0; mi < 2; mi++)
        #pragma unroll
        for(int r = 0; r < 4; r++){
            int qrel = mi * 16 + lg * 4 + r;
            int ro = (b * NC + n) * V + qt * 32 + qrel;
            #pragma unroll
            for(int ni = 0; ni < 2; ni++){
                int col = colbase + ni * 16 + li;
                out[ro * F + col] = oac[mi][ni][r] + b2[col] + xres[mi][ni][r];
            }
        }
}

extern "C" void kernel_launch(void* const* d_in, const int* in_sizes, int n_in,
                              void* d_out, int out_size, void* d_ws, size_t ws_size,
                              hipStream_t stream) {
    const float* code_map = (const float*)d_in[0];
    const float* tex_map  = (const float*)d_in[1];
    const float* Wq = (const float*)d_in[2];  const float* bq = (const float*)d_in[3];
    const float* Wk = (const float*)d_in[4];  const float* bk = (const float*)d_in[5];
    const float* Wv = (const float*)d_in[6];  const float* bv = (const float*)d_in[7];
    const float* Wo = (const float*)d_in[8];  const float* bo = (const float*)d_in[9];
    const float* ln1_g = (const float*)d_in[10]; const float* ln1_b = (const float*)d_in[11];
    const float* ln2_g = (const float*)d_in[12]; const float* ln2_b = (const float*)d_in[13];
    const float* ffln_g = (const float*)d_in[14]; const float* ffln_b = (const float*)d_in[15];
    const float* W1 = (const float*)d_in[16]; const float* b1 = (const float*)d_in[17];
    const float* W2 = (const float*)d_in[18]; const float* b2 = (const float*)d_in[19];
    float* out = (float*)d_out;

    // ws layout (bf16 elements)
    bf16* ws  = (bf16*)d_ws;
    bf16* qn  = ws;                       // 4096*256     = 1048576
    bf16* kn  = qn + 1048576;             // 1048576 (row-major K)
    bf16* v4  = kn + 1048576;             // 1048576 (chunk-tiled V)
    bf16* cn  = v4 + 1048576;             // 1048576
    bf16* tn  = cn + 1048576;             // 1048576
    bf16* tb  = tn + 1048576;             // 1048576 (bf16 texture copy)
    bf16* wbf = tb + 1048576;             // 6*256*256    = 393216 (Wq,Wk,Wv,Wo,W1,W2)

    castw_kernel<<<6 * 64, 256, 0, stream>>>(Wq, Wk, Wv, Wo, W1, W2, wbf);
    ln_kernel<<<2048, 256, 0, stream>>>(code_map, tex_map, ln1_g, ln1_b, ln2_g, ln2_b, cn, tn, tb);
    qkv_kernel<<<dim3(64, 4, 3), 256, 0, stream>>>(cn, tn, wbf, bq, bk, bv, qn, kn, v4);
    attn_mlp_kernel<<<dim3(64, 16), 512, 0, stream>>>(qn, kn, v4, wbf, bo, tb,
                                                      ffln_g, ffln_b, b1, b2, out);
}

// Round 2
// 219.180 us; speedup vs baseline: 1.2245x; 1.2245x over previous
//
#include <hip/hip_runtime.h>
#include <hip/hip_bf16.h>

#define F 256
#define V 512
#define NB 8   // texture batch
#define NC 8   // n_code
#define NH 4
#define DQ 64
#define EPS 1e-6f

typedef __hip_bfloat16 bf16;
typedef __attribute__((ext_vector_type(8))) short short8;   // 8 bf16 MFMA operand
typedef __attribute__((ext_vector_type(4))) float f32x4;    // MFMA accumulator
typedef __attribute__((ext_vector_type(4))) unsigned uint4v;

__device__ __forceinline__ float b2f(bf16 x){ return __bfloat162float(x); }
__device__ __forceinline__ float shf(short s){
    return __bfloat162float(__builtin_bit_cast(bf16, (unsigned short)s));
}

#define MFMA(a,b,c) __builtin_amdgcn_mfma_f32_16x16x32_bf16((a),(b),(c),0,0,0)

__device__ __forceinline__ unsigned pack2bf(float a, float b){
    unsigned short ua = __builtin_bit_cast(unsigned short, __float2bfloat16(a));
    unsigned short ub = __builtin_bit_cast(unsigned short, __float2bfloat16(b));
    return (unsigned)ua | ((unsigned)ub << 16);
}

// ---- K0: fused weight-cast (6x 256x256 fp32 -> bf16) + LayerNorm.
// blocks [0,2048): LN wave-per-row; blocks [2048,2432): castw.
__global__ __launch_bounds__(256) void pre_kernel(const float* __restrict__ code,
                          const float* __restrict__ tex,
                          const float* __restrict__ ln1_g, const float* __restrict__ ln1_b,
                          const float* __restrict__ ln2_g, const float* __restrict__ ln2_b,
                          const float* __restrict__ w0, const float* __restrict__ w1,
                          const float* __restrict__ w2, const float* __restrict__ w3,
                          const float* __restrict__ w4, const float* __restrict__ w5,
                          bf16* __restrict__ cn, bf16* __restrict__ tn, bf16* __restrict__ tb,
                          bf16* __restrict__ wdst){
    if (blockIdx.x >= 2048){
        int bid = blockIdx.x - 2048;
        int which = bid >> 6;
        int idx = (((bid & 63) << 8) | threadIdx.x) << 2;
        const float* s = which==0?w0: which==1?w1: which==2?w2: which==3?w3: which==4?w4: w5;
        float4 v = *(const float4*)(s + idx);
        uint2 p; p.x = pack2bf(v.x, v.y); p.y = pack2bf(v.z, v.w);
        *(uint2*)(wdst + which * (F*F) + idx) = p;
        return;
    }
    int w = threadIdx.x >> 6, lane = threadIdx.x & 63;
    int r = blockIdx.x * 4 + w;
    int is_tex = r >> 12;
    int row = r & 4095;
    const float* src = is_tex ? tex : code;
    const float* g   = is_tex ? ln2_g : ln1_g;
    const float* be  = is_tex ? ln2_b : ln1_b;
    bf16* dst        = is_tex ? tn : cn;

    float4 x = *(const float4*)(src + row * F + lane * 4);
    if (is_tex){
        uint2 p; p.x = pack2bf(x.x, x.y); p.y = pack2bf(x.z, x.w);
        *(uint2*)(tb + row * F + lane * 4) = p;
    }
    float s = x.x + x.y + x.z + x.w;
    #pragma unroll
    for(int m = 1; m < 64; m <<= 1) s += __shfl_xor(s, m);
    float mu = s * (1.0f / F);
    float d0 = x.x - mu, d1 = x.y - mu, d2 = x.z - mu, d3 = x.w - mu;
    float q = d0*d0 + d1*d1 + d2*d2 + d3*d3;
    #pragma unroll
    for(int m = 1; m < 64; m <<= 1) q += __shfl_xor(q, m);
    float rs = rsqrtf(q * (1.0f / F) + EPS);
    float4 gg = *(const float4*)(g + lane * 4);
    float4 bb = *(const float4*)(be + lane * 4);
    uint2 p;
    p.x = pack2bf(d0 * rs * gg.x + bb.x, d1 * rs * gg.y + bb.y);
    p.y = pack2bf(d2 * rs * gg.z + bb.z, d3 * rs * gg.w + bb.w);
    *(uint2*)(dst + row * F + lane * 4) = p;
}

// ---- K2: QKV MFMA GEMM, M=4096 N=256 K=256. grid (64, 4, 3), 4 waves of 16x64.
// z=0: Q -> qn row-major; z=1: K -> k4 A-frag layout; z=2: V -> v4 chunk-tiled.
// All outputs staged through LDS, stored as coalesced 16B chunks (K: wave-contiguous 1KB frags).
__global__ __launch_bounds__(256)
void qkv_kernel(const bf16* __restrict__ cn,
                const bf16* __restrict__ tn,
                const bf16* __restrict__ wbf,
                const float* __restrict__ bq,
                const float* __restrict__ bk,
                const float* __restrict__ bv,
                bf16* __restrict__ qn,
                bf16* __restrict__ k4,
                bf16* __restrict__ v4){
    __shared__ bf16 ts[64][72];
    int which = blockIdx.z;
    const bf16* in   = (which == 0) ? tn : cn;
    const bf16* wb   = wbf + which * (F * F);
    const float* bias = (which == 0) ? bq : (which == 1) ? bk : bv;

    int tid = threadIdx.x;
    int w = tid >> 6, lane = tid & 63;
    int lg = lane >> 4, li = lane & 15;
    int rowbase = blockIdx.x * 64 + w * 16;
    int colbase = blockIdx.y * 64;

    f32x4 acc[4];
    #pragma unroll
    for(int ni = 0; ni < 4; ni++) acc[ni] = (f32x4){0.f,0.f,0.f,0.f};

    const bf16* arow = in + (rowbase + li) * F + lg * 8;
    const bf16* brow = wb + (colbase + li) * F + lg * 8;

    #pragma unroll
    for(int kc = 0; kc < 8; kc++){
        short8 a = *(const short8*)(arow + kc * 32);
        #pragma unroll
        for(int ni = 0; ni < 4; ni++){
            short8 bbf = *(const short8*)(brow + ni * 16 * F + kc * 32);
            acc[ni] = MFMA(a, bbf, acc[ni]);
        }
    }

    // stage (acc + bias) to LDS; V transposed [col][key_local], Q/K as [key_local][col]
    if (which < 2){
        #pragma unroll
        for(int ni = 0; ni < 4; ni++)
            #pragma unroll
            for(int r = 0; r < 4; r++)
                ts[w * 16 + lg * 4 + r][ni * 16 + li] =
                    __float2bfloat16(acc[ni][r] + bias[colbase + ni * 16 + li]);
    } else {
        #pragma unroll
        for(int ni = 0; ni < 4; ni++)
            #pragma unroll
            for(int r = 0; r < 4; r++)
                ts[ni * 16 + li][w * 16 + lg * 4 + r] =
                    __float2bfloat16(acc[ni][r] + bias[colbase + ni * 16 + li]);
    }
    __syncthreads();

    if (which == 0){
        int rr = tid >> 2, gg2 = tid & 3;
        *(short8*)(qn + (blockIdx.x * 64 + rr) * F + colbase + gg2 * 16)
            = *(const short8*)&ts[rr][gg2 * 16];
    } else if (which == 1){
        // k4 fragment layout: fi = ((n*16+kc2)*2+kt)*8 + hh*2 + ks ; elem lgp*128+lip*8+j
        int n = blockIdx.x >> 3;
        int kc2base = (blockIdx.x & 7) * 2;
        int hh = blockIdx.y;
        #pragma unroll
        for(int rep = 0; rep < 2; rep++){
            int c = tid + 256 * rep;
            int f = c >> 6, wf = c & 63;
            int lgp = wf >> 4, lip = wf & 15;
            int kc2l = f >> 2, kt = (f >> 1) & 1, ks = f & 1;
            int fi = ((n * 16 + kc2base + kc2l) * 2 + kt) * 8 + hh * 2 + ks;
            *(short8*)(k4 + fi * 512 + lgp * 128 + lip * 8)
                = *(const short8*)&ts[kc2l * 32 + kt * 16 + lip][ks * 32 + lgp * 8];
        }
    } else {
        int col = tid & 63, half = tid >> 6;
        int keybase = blockIdx.x * 64;
        int n = keybase >> 9;
        int keyl = (keybase & (V - 1)) + half * 16;
        int chunk = keyl >> 5, off = keyl & 31;
        *(short8*)(v4 + ((n * 16 + chunk) * F + colbase + col) * 32 + off)
            = *(const short8*)&ts[col][half * 16];
    }
}

// ---- K3 MEGA: flash attention + Wo + tex residual + ffln LN + W1/ReLU + W2 + residual -> out.
// grid (64, 16): x encodes (n = x&7 -> XCD swizzle, b = x>>3), y = qtile. 512 thr = 8 waves.
// Flash: wave = (head h, q-half qh), 16 q x 64 d, explicit next-chunk prefetch, no LDS/barriers.
// Then block holds 32 full x rows: MLP runs entirely in LDS/registers; out written directly.
__global__ __launch_bounds__(512, 4) void attn_mlp_kernel(const bf16* __restrict__ qn,
                                                          const bf16* __restrict__ k4,
                                                          const bf16* __restrict__ v4,
                                                          const bf16* __restrict__ wbf,
                                                          const float* __restrict__ bo,
                                                          const bf16* __restrict__ tb,
                                                          const float* __restrict__ ffg,
                                                          const float* __restrict__ ffb,
                                                          const float* __restrict__ b1,
                                                          const float* __restrict__ b2,
                                                          float* __restrict__ out){
    __shared__ bf16 xs[32][264];        // ctx -> x -> xhat -> h1 (reused)
    __shared__ float red[512], red2[512];
    __shared__ float stat[32][2];
    int n = blockIdx.x & 7, b = blockIdx.x >> 3, qt = blockIdx.y;
    int tid = threadIdx.x;
    int w = tid >> 6, lane = tid & 63;
    int h = w & 3, qh = w >> 2;
    int lg = lane >> 4, li = lane & 15;

    // Q B-frag resident
    short8 qB[2];
    #pragma unroll
    for(int ks = 0; ks < 2; ks++)
        qB[ks] = *(const short8*)(qn + (b * V + qt * 32 + qh * 16 + li) * F
                                     + h * DQ + ks * 32 + lg * 8);

    f32x4 o[4];
    #pragma unroll
    for(int dt = 0; dt < 4; dt++) o[dt] = (f32x4){0.f,0.f,0.f,0.f};
    float l_acc = 0.f;

    const float scale = 0.125f;
    int g1 = lg & 1;
    int lhA = li | ((2 * g1) << 4);
    int lhB = lhA | 16;
    bool hi = lane >= 32;
    int fel = lg * 128 + li * 8;

    // prefetch chunk 0
    short8 kA0, kA1, kA2, kA3, vA0, vA1, vA2, vA3;
    {
        int fb = ((n * 16 + 0) * 2) * 8 + h * 2;
        kA0 = *(const short8*)(k4 + (fb + 0) * 512 + fel);
        kA1 = *(const short8*)(k4 + (fb + 1) * 512 + fel);
        kA2 = *(const short8*)(k4 + (fb + 8) * 512 + fel);
        kA3 = *(const short8*)(k4 + (fb + 9) * 512 + fel);
        const bf16* vb = v4 + ((n * 16 + 0) * F + h * DQ) * 32;
        vA0 = *(const short8*)(vb + (0 * 16 + li) * 32 + lg * 8);
        vA1 = *(const short8*)(vb + (1 * 16 + li) * 32 + lg * 8);
        vA2 = *(const short8*)(vb + (2 * 16 + li) * 32 + lg * 8);
        vA3 = *(const short8*)(vb + (3 * 16 + li) * 32 + lg * 8);
    }

    #pragma unroll
    for(int kc = 0; kc < 16; kc++){
        short8 nk0, nk1, nk2, nk3, nv0, nv1, nv2, nv3;
        if (kc < 15){
            int fb = ((n * 16 + kc + 1) * 2) * 8 + h * 2;
            nk0 = *(const short8*)(k4 + (fb + 0) * 512 + fel);
            nk1 = *(const short8*)(k4 + (fb + 1) * 512 + fel);
            nk2 = *(const short8*)(k4 + (fb + 8) * 512 + fel);
            nk3 = *(const short8*)(k4 + (fb + 9) * 512 + fel);
            const bf16* vb = v4 + ((n * 16 + kc + 1) * F + h * DQ) * 32;
            nv0 = *(const short8*)(vb + (0 * 16 + li) * 32 + lg * 8);
            nv1 = *(const short8*)(vb + (1 * 16 + li) * 32 + lg * 8);
            nv2 = *(const short8*)(vb + (2 * 16 + li) * 32 + lg * 8);
            nv3 = *(const short8*)(vb + (3 * 16 + li) * 32 + lg * 8);
        }

        // S^T = K·Q^T
        f32x4 st0 = (f32x4){0.f,0.f,0.f,0.f};
        f32x4 st1 = (f32x4){0.f,0.f,0.f,0.f};
        __builtin_amdgcn_s_setprio(1);
        st0 = MFMA(kA0, qB[0], st0);
        st1 = MFMA(kA2, qB[0], st1);
        st0 = MFMA(kA1, qB[1], st0);
        st1 = MFMA(kA3, qB[1], st1);
        __builtin_amdgcn_s_setprio(0);

        // exp (no max: bounded scores, ratio-invariant)
        float p[2][4], rsum = 0.f;
        #pragma unroll
        for(int r = 0; r < 4; r++){
            p[0][r] = __expf(st0[r] * scale);
            p[1][r] = __expf(st1[r] * scale);
            rsum += p[0][r] + p[1][r];
        }
        l_acc += rsum;

        unsigned pk00 = pack2bf(p[0][0], p[0][1]);
        unsigned pk01 = pack2bf(p[0][2], p[0][3]);
        unsigned pk10 = pack2bf(p[1][0], p[1][1]);
        unsigned pk11 = pack2bf(p[1][2], p[1][3]);

        unsigned d0a = __shfl((int)pk00, lhA, 64);
        unsigned d0b = __shfl((int)pk10, lhA, 64);
        unsigned d1a = __shfl((int)pk01, lhA, 64);
        unsigned d1b = __shfl((int)pk11, lhA, 64);
        unsigned d2a = __shfl((int)pk00, lhB, 64);
        unsigned d2b = __shfl((int)pk10, lhB, 64);
        unsigned d3a = __shfl((int)pk01, lhB, 64);
        unsigned d3b = __shfl((int)pk11, lhB, 64);
        uint4v uv;
        uv.x = hi ? d0b : d0a;
        uv.y = hi ? d1b : d1a;
        uv.z = hi ? d2b : d2a;
        uv.w = hi ? d3b : d3a;
        short8 pfrag = __builtin_bit_cast(short8, uv);

        __builtin_amdgcn_s_setprio(1);
        o[0] = MFMA(vA0, pfrag, o[0]);
        o[1] = MFMA(vA1, pfrag, o[1]);
        o[2] = MFMA(vA2, pfrag, o[2]);
        o[3] = MFMA(vA3, pfrag, o[3]);
        __builtin_amdgcn_s_setprio(0);

        kA0 = nk0; kA1 = nk1; kA2 = nk2; kA3 = nk3;
        vA0 = nv0; vA1 = nv1; vA2 = nv2; vA3 = nv3;
    }

    l_acc += __shfl_xor(l_acc, 16);
    l_acc += __shfl_xor(l_acc, 32);
    float inv = 1.0f / l_acc;

    // stage normalized O to LDS as ctx[qrel][col]
    #pragma unroll
    for(int dt = 0; dt < 4; dt++){
        uint2 pkd;
        pkd.x = pack2bf(o[dt][0] * inv, o[dt][1] * inv);
        pkd.y = pack2bf(o[dt][2] * inv, o[dt][3] * inv);
        *(uint2*)&xs[qh * 16 + li][h * DQ + dt * 16 + lg * 4] = pkd;
    }
    __syncthreads();

    // ---- Wo GEMM + bo + tex residual -> xres (registers, fp32)
    const bf16* Wo = wbf + 3 * (F * F);
    int colbase = w * 32;
    f32x4 xac[2][2];
    #pragma unroll
    for(int mi = 0; mi < 2; mi++)
        #pragma unroll
        for(int ni = 0; ni < 2; ni++) xac[mi][ni] = (f32x4){0.f,0.f,0.f,0.f};
    #pragma unroll
    for(int kc = 0; kc < 8; kc++){
        short8 a0 = *(const short8*)&xs[li][kc * 32 + lg * 8];
        short8 a1 = *(const short8*)&xs[16 + li][kc * 32 + lg * 8];
        #pragma unroll
        for(int ni = 0; ni < 2; ni++){
            short8 bw = *(const short8*)(Wo + (colbase + ni * 16 + li) * F + kc * 32 + lg * 8);
            xac[0][ni] = MFMA(a0, bw, xac[0][ni]);
            xac[1][ni] = MFMA(a1, bw, xac[1][ni]);
        }
    }
    float xres[2][2][4];
    #pragma unroll
    for(int mi = 0; mi < 2; mi++)
        #pragma unroll
        for(int r = 0; r < 4; r++){
            int qrel = mi * 16 + lg * 4 + r;
            #pragma unroll
            for(int ni = 0; ni < 2; ni++){
                int col = colbase + ni * 16 + li;
                xres[mi][ni][r] = xac[mi][ni][r] + bo[col]
                                + b2f(tb[(b * V + qt * 32 + qrel) * F + col]);
            }
        }
    __syncthreads();                  // all ctx reads done
    // write x (bf16) into xs
    #pragma unroll
    for(int mi = 0; mi < 2; mi++)
        #pragma unroll
        for(int r = 0; r < 4; r++){
            int qrel = mi * 16 + lg * 4 + r;
            #pragma unroll
            for(int ni = 0; ni < 2; ni++)
                xs[qrel][colbase + ni * 16 + li] = __float2bfloat16(xres[mi][ni][r]);
        }
    __syncthreads();

    // ---- ffln LN: 16 threads per row, one-pass (E[x^2]-mu^2)
    int row = tid >> 4, sub = tid & 15;
    short8 xa = *(const short8*)&xs[row][sub * 16];
    short8 xb2 = *(const short8*)&xs[row][sub * 16 + 8];
    float sum = 0.f, sq = 0.f;
    #pragma unroll
    for(int j = 0; j < 8; j++){
        float v0 = shf(xa[j]), v1 = shf(xb2[j]);
        sum += v0 + v1; sq += v0 * v0 + v1 * v1;
    }
    red[tid] = sum; red2[tid] = sq;
    __syncthreads();
    if (tid < 32){
        float s = 0.f, q2 = 0.f;
        #pragma unroll
        for(int i = 0; i < 16; i++){ s += red[tid * 16 + i]; q2 += red2[tid * 16 + i]; }
        float mu = s * (1.0f / F);
        float var = q2 * (1.0f / F) - mu * mu;
        stat[tid][0] = mu;
        stat[tid][1] = rsqrtf(var + EPS);
    }
    __syncthreads();
    {
        float mu = stat[row][0], rsv = stat[row][1];
        float nv[16];
        #pragma unroll
        for(int j = 0; j < 8; j++){
            int c0 = sub * 16 + j, c1 = sub * 16 + 8 + j;
            nv[j]     = (shf(xa[j])  - mu) * rsv * ffg[c0] + ffb[c0];
            nv[8 + j] = (shf(xb2[j]) - mu) * rsv * ffg[c1] + ffb[c1];
        }
        uint4v pa, pb;
        pa.x = pack2bf(nv[0], nv[1]);  pa.y = pack2bf(nv[2], nv[3]);
        pa.z = pack2bf(nv[4], nv[5]);  pa.w = pack2bf(nv[6], nv[7]);
        pb.x = pack2bf(nv[8], nv[9]);  pb.y = pack2bf(nv[10], nv[11]);
        pb.z = pack2bf(nv[12], nv[13]); pb.w = pack2bf(nv[14], nv[15]);
        *(short8*)&xs[row][sub * 16]     = __builtin_bit_cast(short8, pa);
        *(short8*)&xs[row][sub * 16 + 8] = __builtin_bit_cast(short8, pb);
    }
    __syncthreads();

    // ---- GEMM1: h = relu(xhat @ W1^T + b1), wave cols w*32..+32
    const bf16* W1b = wbf + 4 * (F * F);
    f32x4 hac[2][2];
    #pragma unroll
    for(int mi = 0; mi < 2; mi++)
        #pragma unroll
        for(int ni = 0; ni < 2; ni++) hac[mi][ni] = (f32x4){0.f,0.f,0.f,0.f};
    #pragma unroll
    for(int kc = 0; kc < 8; kc++){
        short8 a0 = *(const short8*)&xs[li][kc * 32 + lg * 8];
        short8 a1 = *(const short8*)&xs[16 + li][kc * 32 + lg * 8];
        #pragma unroll
        for(int ni = 0; ni < 2; ni++){
            short8 bw = *(const short8*)(W1b + (colbase + ni * 16 + li) * F + kc * 32 + lg * 8);
            hac[0][ni] = MFMA(a0, bw, hac[0][ni]);
            hac[1][ni] = MFMA(a1, bw, hac[1][ni]);
        }
    }
    __syncthreads();                  // xhat reads done
    #pragma unroll
    for(int mi = 0; mi < 2; mi++)
        #pragma unroll
        for(int r = 0; r < 4; r++){
            int rr = mi * 16 + lg * 4 + r;
            #pragma unroll
            for(int ni = 0; ni < 2; ni++){
                int col = colbase + ni * 16 + li;
                xs[rr][col] = __float2bfloat16(fmaxf(hac[mi][ni][r] + b1[col], 0.f));
            }
        }
    __syncthreads();

    // ---- GEMM2: out = x + h @ W2^T + b2
    const bf16* W2b = wbf + 5 * (F * F);
    f32x4 oac[2][2];
    #pragma unroll
    for(int mi = 0; mi < 2; mi++)
        #pragma unroll
        for(int ni = 0; ni < 2; ni++) oac[mi][ni] = (f32x4){0.f,0.f,0.f,0.f};
    #pragma unroll
    for(int kc = 0; kc < 8; kc++){
        short8 a0 = *(const short8*)&xs[li][kc * 32 + lg * 8];
        short8 a1 = *(const short8*)&xs[16 + li][kc * 32 + lg * 8];
        #pragma unroll
        for(int ni = 0; ni < 2; ni++){
            short8 bw = *(const short8*)(W2b + (colbase + ni * 16 + li) * F + kc * 32 + lg * 8);
            oac[0][ni] = MFMA(a0, bw, oac[0][ni]);
            oac[1][ni] = MFMA(a1, bw, oac[1][ni]);
        }
    }
    #pragma unroll
    for(int mi = 0; mi < 2; mi++)
        #pragma unroll
        for(int r = 0; r < 4; r++){
            int qrel = mi * 16 + lg * 4 + r;
            int ro = (b * NC + n) * V + qt * 32 + qrel;
            #pragma unroll
            for(int ni = 0; ni < 2; ni++){
                int col = colbase + ni * 16 + li;
                out[ro * F + col] = oac[mi][ni][r] + b2[col] + xres[mi][ni][r];
            }
        }
}

extern "C" void kernel_launch(void* const* d_in, const int* in_sizes, int n_in,
                              void* d_out, int out_size, void* d_ws, size_t ws_size,
                              hipStream_t stream) {
    const float* code_map = (const float*)d_in[0];
    const float* tex_map  = (const float*)d_in[1];
    const float* Wq = (const float*)d_in[2];  const float* bq = (const float*)d_in[3];
    const float* Wk = (const float*)d_in[4];  const float* bk = (const float*)d_in[5];
    const float* Wv = (const float*)d_in[6];  const float* bv = (const float*)d_in[7];
    const float* Wo = (const float*)d_in[8];  const float* bo = (const float*)d_in[9];
    const float* ln1_g = (const float*)d_in[10]; const float* ln1_b = (const float*)d_in[11];
    const float* ln2_g = (const float*)d_in[12]; const float* ln2_b = (const float*)d_in[13];
    const float* ffln_g = (const float*)d_in[14]; const float* ffln_b = (const float*)d_in[15];
    const float* W1 = (const float*)d_in[16]; const float* b1 = (const float*)d_in[17];
    const float* W2 = (const float*)d_in[18]; const float* b2 = (const float*)d_in[19];
    float* out = (float*)d_out;

    // ws layout (bf16 elements)
    bf16* ws  = (bf16*)d_ws;
    bf16* qn  = ws;                       // 4096*256     = 1048576
    bf16* k4  = qn + 1048576;             // 1048576 (A-frag layout)
    bf16* v4  = k4 + 1048576;             // 1048576 (chunk-tiled V)
    bf16* cn  = v4 + 1048576;             // 1048576
    bf16* tn  = cn + 1048576;             // 1048576
    bf16* tb  = tn + 1048576;             // 1048576 (bf16 texture copy)
    bf16* wbf = tb + 1048576;             // 6*256*256    = 393216 (Wq,Wk,Wv,Wo,W1,W2)

    pre_kernel<<<2048 + 384, 256, 0, stream>>>(code_map, tex_map, ln1_g, ln1_b, ln2_g, ln2_b,
                                               Wq, Wk, Wv, Wo, W1, W2, cn, tn, tb, wbf);
    qkv_kernel<<<dim3(64, 4, 3), 256, 0, stream>>>(cn, tn, wbf, bq, bk, bv, qn, k4, v4);
    attn_mlp_kernel<<<dim3(64, 16), 512, 0, stream>>>(qn, k4, v4, wbf, bo, tb,
                                                      ffln_g, ffln_b, b1, b2, out);
}